// Round 11
// baseline (1668.781 us; speedup 1.0000x reference)
//
#include <hip/hip_runtime.h>
#include <math.h>

// Problem constants
#define NCOMP 20000
#define SEQT  32
#define INSZ  64
#define HSZ   128
#define EINTRA 640000
#define EINTER 4096
#define NSEC  64

#define LDH 132   // padded LDS row stride (floats) for gat_transform

typedef __attribute__((ext_vector_type(8))) short bf16x8;   // 8 bf16 in 4 VGPRs
typedef __attribute__((ext_vector_type(4))) float f32x4;    // MFMA C/D frag

__device__ __forceinline__ float dot4f(float4 a, float4 b){
  return a.x*b.x + a.y*b.y + a.z*b.z + a.w*b.w;
}
__device__ __forceinline__ float sigm(float x){ return 1.f/(1.f + __expf(-x)); }
__device__ __forceinline__ float ftanh(float x){
  float cx = fminf(fmaxf(x, -15.f), 15.f);
  float e = __expf(2.f*cx);
  return (e - 1.f)/(e + 1.f);
}
// monotone float<->uint mapping so atomicMax works for signed floats (inter path)
__device__ __forceinline__ unsigned fordu(float f){
  unsigned b = __float_as_uint(f);
  return (b & 0x80000000u) ? ~b : (b | 0x80000000u);
}
__device__ __forceinline__ float unfordu(unsigned u){
  unsigned b = (u & 0x80000000u) ? (u & 0x7fffffffu) : ~u;
  return __uint_as_float(b);
}
#define NEG_MAX_ORD 0x00800000u   // fordu(-FLT_MAX)

// bf16 hi/lo split helpers (truncation split: w = hi + rem exactly, lo = bf16(rem))
__device__ __forceinline__ unsigned short bf16hi(float f){
  return (unsigned short)(__float_as_uint(f) >> 16);
}
__device__ __forceinline__ float bf16tof(unsigned short h){
  return __uint_as_float(((unsigned)h) << 16);
}

// ===========================================================================
// Weight packing for MFMA bf16x3: out[(kt*24+nt)*2+{hi,lo}][lane][8 bf16].
// Fragment convention (must match A-side): col n = lane&15 (within nt tile),
// k = kt*32 + (lane>>4)*8 + j.  One coalesced dwordx4 per fragment at use.
// (UNCHANGED from rounds 5-10 — layout verified correct by passing refchecks.)
// ===========================================================================
__global__ void wpack_mfma(const float* __restrict__ W, unsigned short* __restrict__ out, int K)
{
  int tid = blockIdx.x*256 + threadIdx.x;
  int KT = K >> 5;
  if (tid >= KT*24*64) return;
  int lane = tid & 63;
  int nt   = (tid >> 6) % 24;
  int kt   = (tid >> 6) / 24;
  int col  = nt*16 + (lane & 15);
  int kbase = kt*32 + (lane >> 4)*8;
  size_t b = ((size_t)(kt*24 + nt)*2*64 + lane)*8;   // hi at b, lo at b+512
  #pragma unroll
  for (int j = 0; j < 8; ++j){
    float w = W[(size_t)col*K + kbase + j];
    unsigned short h = bf16hi(w);
    float rem = w - bf16tof(h);
    out[b + j]       = h;
    out[b + 512 + j] = bf16hi(rem);
  }
}

// ===========================================================================
// MFMA bf16x3 fused 2-layer GRU, v3.4: occupancy-pinned register budget.
// Block = 512 thr (8 waves) = 80 companies (5 M-tiles), grid 250 (exact).
// Wave w owns dim-slice [16w, 16w+16) -> B-tiles {w, 8+w, 16+w} (R/Z/N).
// ROUND-10 DIAGNOSIS: kernel is bound on 2.2 GB/dispatch of residual HBM
// traffic; ~141 MB/dispatch is scratch-SPILL writes plus ~GBs of reloads.
// The allocator pins VGPR at the 128 occupancy step and spills ~9 dwords/
// thread/t, even though LDS (102 KB) fixes occupancy at 1 block/CU =
// 2 waves/SIMD where a 256-VGPR budget is free. launch_bounds only sets
// MIN waves/EU; amdgpu_waves_per_eu(2,2) pins the occupancy TARGET to the
// real value -> VGPR budget 256 -> the ~140-reg true demand fits, no spill.
// Everything else (layouts, math, barriers, STAGEX x-dedup) unchanged.
// ===========================================================================
__global__ __launch_bounds__(512)
__attribute__((amdgpu_waves_per_eu(2, 2)))
void gru_mfma(const float* __restrict__ x,
              const unsigned short* __restrict__ w0pk, const unsigned short* __restrict__ u0pk,
              const unsigned short* __restrict__ w1pk, const unsigned short* __restrict__ u1pk,
              const float* __restrict__ bih0, const float* __restrict__ bhh0,
              const float* __restrict__ bih1, const float* __restrict__ bhh1,
              float* __restrict__ seq)
{
  // [layer][hi/lo][kt][mtile][lane][8] : 2*2*4*5*64*8*2B = 80 KB
  __shared__ __align__(16) unsigned short hfr[2][2][4][5][64][8];
  // x fragments for current t: [kt][mtile][hi/lo][lane][8] = 20.5 KB
  __shared__ __align__(16) unsigned short xfr[2][5][2][64][8];

  const int tid = threadIdx.x;
  const int w = tid >> 6, l = tid & 63;
  const int cq = l & 15, kg = l >> 4;
  const int cbase = blockIdx.x*80;          // 250*80 == 20000 exactly, no tail
  const int d = w*16 + cq;                  // this thread's output dim [0,128)
  const int ktp = d >> 5, kgp = (d >> 3) & 3, jp = d & 7;  // h-frag cell for dim d

  // zero h state
  {
    float4 z4 = make_float4(0.f,0.f,0.f,0.f);
    float4* hz = (float4*)&hfr[0][0][0][0][0][0];
    for (int i = tid; i < 5120; i += 512) hz[i] = z4;   // 80 KB
  }
  // biases in registers (dim d fixed per thread)
  const float bR0 = bih0[d]       + bhh0[d];
  const float bZ0 = bih0[128 + d] + bhh0[128 + d];
  const float bX0 = bih0[256 + d];
  const float bH0 = bhh0[256 + d];
  const float bR1 = bih1[d]       + bhh1[d];
  const float bZ1 = bih1[128 + d] + bhh1[128 + d];
  const float bX1 = bih1[256 + d];
  const float bH1 = bhh1[256 + d];

  // stage x fragments for a timestep TT into xfr (once per block, not per wave).
  // fi covers (mt 0..4, kt 0..1, lane 0..63): each thread converts one 8-elem
  // fragment pair (hi+lo). ds_write_b128 lane-sequential => conflict-free.
  #define STAGEX(TT) do { \
    _Pragma("unroll") for (int it = 0; it < 2; ++it){ \
      int fi = tid + it*512; \
      if (fi < 640){ \
        int slane = fi & 63, q = fi >> 6; \
        int skt = q & 1, smt = q >> 1; \
        const float* sp = x + ((size_t)(cbase + smt*16 + (slane & 15))*SEQT + (TT))*INSZ \
                            + skt*32 + (slane >> 4)*8; \
        float4 q0 = *(const float4*)sp; \
        float4 q1 = *(const float4*)(sp + 4); \
        float xf[8] = {q0.x,q0.y,q0.z,q0.w, q1.x,q1.y,q1.z,q1.w}; \
        bf16x8 hv, lv; \
        _Pragma("unroll") for (int j = 0; j < 8; ++j){ \
          unsigned short h_ = bf16hi(xf[j]); \
          hv[j] = (short)h_; \
          lv[j] = (short)bf16hi(xf[j] - bf16tof(h_)); } \
        *(bf16x8*)&xfr[skt][smt][0][slane][0] = hv; \
        *(bf16x8*)&xfr[skt][smt][1][slane][0] = lv; } } \
  } while(0)

  STAGEX(0);
  __syncthreads();

  f32x4 cR[5], cZ[5], cN[5], cH[5];

  #define CINIT(BR,BZ,BX,BH) do { \
    _Pragma("unroll") for (int mt = 0; mt < 5; ++mt){ \
      cR[mt] = (f32x4){BR,BR,BR,BR}; \
      cZ[mt] = (f32x4){BZ,BZ,BZ,BZ}; \
      cN[mt] = (f32x4){BX,BX,BX,BX}; \
      cH[mt] = (f32x4){BH,BH,BH,BH}; } \
  } while(0)

  #define MF3(AH, AL, BH, BL, C) do { \
    C = __builtin_amdgcn_mfma_f32_16x16x32_bf16(AH, BH, C, 0,0,0); \
    C = __builtin_amdgcn_mfma_f32_16x16x32_bf16(AH, BL, C, 0,0,0); \
    C = __builtin_amdgcn_mfma_f32_16x16x32_bf16(AL, BH, C, 0,0,0); \
  } while(0)

  // one kt-slab, A = h fragments: 6 B-frags resident, A streamed per mt.
  #define GEMSLAB(PK, KT, LYR, C2) do { \
    const unsigned short* _p = (PK) + (size_t)(KT)*24576 + (size_t)l*8; \
    const bf16x8* bp0 = (const bf16x8*)(_p + (size_t)w*1024); \
    const bf16x8* bp1 = (const bf16x8*)(_p + (size_t)(8 + w)*1024); \
    const bf16x8* bp2 = (const bf16x8*)(_p + (size_t)(16 + w)*1024); \
    bf16x8 bh0 = bp0[0], bl0 = bp0[64]; \
    bf16x8 bh1 = bp1[0], bl1 = bp1[64]; \
    bf16x8 bh2 = bp2[0], bl2 = bp2[64]; \
    _Pragma("unroll") for (int mt = 0; mt < 5; ++mt){ \
      bf16x8 ah = *(const bf16x8*)&hfr[LYR][0][KT][mt][l][0]; \
      bf16x8 al = *(const bf16x8*)&hfr[LYR][1][KT][mt][l][0]; \
      MF3(ah, al, bh0, bl0, cR[mt]); \
      MF3(ah, al, bh1, bl1, cZ[mt]); \
      MF3(ah, al, bh2, bl2, C2[mt]); } \
  } while(0)

  // one kt-slab, A = staged x fragments from LDS (layer-0 input, K=64)
  #define GEMSLABX(KT) do { \
    const unsigned short* _p = w0pk + (size_t)(KT)*24576 + (size_t)l*8; \
    const bf16x8* bp0 = (const bf16x8*)(_p + (size_t)w*1024); \
    const bf16x8* bp1 = (const bf16x8*)(_p + (size_t)(8 + w)*1024); \
    const bf16x8* bp2 = (const bf16x8*)(_p + (size_t)(16 + w)*1024); \
    bf16x8 bh0 = bp0[0], bl0 = bp0[64]; \
    bf16x8 bh1 = bp1[0], bl1 = bp1[64]; \
    bf16x8 bh2 = bp2[0], bl2 = bp2[64]; \
    _Pragma("unroll") for (int mt = 0; mt < 5; ++mt){ \
      bf16x8 ah = *(const bf16x8*)&xfr[KT][mt][0][l][0]; \
      bf16x8 al = *(const bf16x8*)&xfr[KT][mt][1][l][0]; \
      MF3(ah, al, bh0, bl0, cR[mt]); \
      MF3(ah, al, bh1, bl1, cZ[mt]); \
      MF3(ah, al, bh2, bl2, cN[mt]); } \
  } while(0)

  // GRU elementwise for this thread's dim d across 5 mt x 4 comps.
  // C/D layout (m89-verified): col=cq (dim-in-tile), row=kg*4+r (comp).
  #define ELEM(LYR, DOSTORE) do { \
    _Pragma("unroll") for (int mt = 0; mt < 5; ++mt){ \
      unsigned short* hhi = &hfr[LYR][0][ktp][mt][0][0]; \
      unsigned short* hlo = &hfr[LYR][1][ktp][mt][0][0]; \
      _Pragma("unroll") for (int r = 0; r < 4; ++r){ \
        int lanep = kgp*16 + kg*4 + r; \
        float hold = bf16tof(hhi[lanep*8 + jp]) + bf16tof(hlo[lanep*8 + jp]); \
        float rr = sigm(cR[mt][r]); \
        float zz = sigm(cZ[mt][r]); \
        float nn = ftanh(cN[mt][r] + rr*cH[mt][r]); \
        float hn = (1.f - zz)*nn + zz*hold; \
        unsigned short hh = bf16hi(hn); \
        hhi[lanep*8 + jp] = hh; \
        hlo[lanep*8 + jp] = bf16hi(hn - bf16tof(hh)); \
        if (DOSTORE) seq[(size_t)(cbase + mt*16 + kg*4 + r)*HSZ + d] = hn; } } \
  } while(0)

  #pragma unroll 1
  for (int t = 0; t < SEQT; ++t){
    // ================= layer 0 =================
    CINIT(bR0, bZ0, bX0, bH0);
    GEMSLABX(0);                       // x part, K=64 (A from staged LDS)
    GEMSLABX(1);
    GEMSLAB(u0pk, 0, 0, cH);           // h part, K=128 (A = h0_old)
    GEMSLAB(u0pk, 1, 0, cH);
    GEMSLAB(u0pk, 2, 0, cH);
    GEMSLAB(u0pk, 3, 0, cH);
    __syncthreads();                   // all waves done reading h0_old (and xfr)
    ELEM(0, false);
    __syncthreads();                   // h0_new visible
    // ================= layer 1 =================
    CINIT(bR1, bZ1, bX1, bH1);
    GEMSLAB(w1pk, 0, 0, cN);           // input = h0_new
    GEMSLAB(w1pk, 1, 0, cN);
    GEMSLAB(w1pk, 2, 0, cN);
    GEMSLAB(w1pk, 3, 0, cN);
    GEMSLAB(u1pk, 0, 1, cH);           // hidden h1_old
    GEMSLAB(u1pk, 1, 1, cH);
    GEMSLAB(u1pk, 2, 1, cH);
    GEMSLAB(u1pk, 3, 1, cH);
    __syncthreads();                   // all waves done reading h1_old
    ELEM(1, (t == SEQT-1));
    if (t + 1 < SEQT) STAGEX(t + 1);   // stage next-t x (xfr reads done at sync#1)
    __syncthreads();                   // h1_new + xfr visible for next t
  }
  #undef CINIT
  #undef MF3
  #undef GEMSLAB
  #undef GEMSLABX
  #undef ELEM
  #undef STAGEX
}

// ===========================================================================
// GAT stage — CSR build + atomic-free per-node gather
// ===========================================================================
__global__ __launch_bounds__(256)
void gat_transform(const float* __restrict__ X, const float* __restrict__ W,
                   const float* __restrict__ asrc, const float* __restrict__ adst,
                   float* __restrict__ Hout, float* __restrict__ es, float* __restrict__ ed,
                   int n)
{
  __shared__ float sX[64*LDH];
  const int tid = threadIdx.x;
  const long base = (long)blockIdx.x * 64;
  for (int i = tid; i < 64*32; i += 256){
    int row = i >> 5, q = i & 31;
    long gr = base + row;
    float4 v = make_float4(0.f, 0.f, 0.f, 0.f);
    if (gr < n) v = ((const float4*)(X + gr*HSZ))[q];
    ((float4*)(sX + row*LDH))[q] = v;
  }
  __syncthreads();
  const int rp = tid >> 3, dg = tid & 7;
  const int r0 = rp*2, r1 = r0 + 1;
  const float4* xa = (const float4*)(sX + r0*LDH);
  const float4* xb = (const float4*)(sX + r1*LDH);
  float ps0=0.f, pd0=0.f, ps1=0.f, pd1=0.f;
  for (int dd = 0; dd < 16; ++dd){
    const int cidx = dg*16 + dd;
    const float4* wp = (const float4*)(W + cidx*HSZ);
    float a0 = 0.f, a1 = 0.f;
    #pragma unroll 4
    for (int q = 0; q < 32; ++q){
      float4 w = wp[q];
      a0 += dot4f(w, xa[q]);
      a1 += dot4f(w, xb[q]);
    }
    float s = asrc[cidx], dv = adst[cidx];
    ps0 += a0*s; pd0 += a0*dv;
    ps1 += a1*s; pd1 += a1*dv;
    if (base + r0 < n) Hout[(base+r0)*HSZ + cidx] = a0;
    if (base + r1 < n) Hout[(base+r1)*HSZ + cidx] = a1;
  }
  #pragma unroll
  for (int m = 1; m < 8; m <<= 1){
    ps0 += __shfl_xor(ps0, m, 64);
    pd0 += __shfl_xor(pd0, m, 64);
    ps1 += __shfl_xor(ps1, m, 64);
    pd1 += __shfl_xor(pd1, m, 64);
  }
  if (dg == 0){
    if (base + r0 < n){ es[base+r0] = ps0; ed[base+r0] = pd0; }
    if (base + r1 < n){ es[base+r1] = ps1; ed[base+r1] = pd1; }
  }
}

__global__ void zero_i(int* __restrict__ p, int n)
{
  int i = blockIdx.x*256 + threadIdx.x;
  if (i < n) p[i] = 0;
}

__global__ void csr_count(const int* __restrict__ key, int* __restrict__ cnt, int E)
{
  int i = blockIdx.x*256 + threadIdx.x;
  if (i < E) atomicAdd(&cnt[key[i]], 1);
}

// single block, 1024 threads: exclusive scan of cnt[0..n) -> rowptr, cursor
__global__ __launch_bounds__(1024)
void csr_scan(const int* __restrict__ cnt, int* __restrict__ rowptr,
              int* __restrict__ cursor, int n)
{
  __shared__ int ls[1024];
  const int t = threadIdx.x;
  const int base = t*20;
  int loc[20];
  int s = 0;
  #pragma unroll
  for (int k = 0; k < 20; ++k){
    int idx = base + k;
    int v = (idx < n) ? cnt[idx] : 0;
    loc[k] = s; s += v;
  }
  ls[t] = s;
  __syncthreads();
  for (int off = 1; off < 1024; off <<= 1){
    int v = (t >= off) ? ls[t-off] : 0;
    __syncthreads();
    ls[t] += v;
    __syncthreads();
  }
  int excl = (t == 0) ? 0 : ls[t-1];
  #pragma unroll
  for (int k = 0; k < 20; ++k){
    int idx = base + k;
    if (idx < n){ int rp = excl + loc[k]; rowptr[idx] = rp; cursor[idx] = rp; }
  }
  if (t == 1023) rowptr[n] = ls[1023];
}

// val==nullptr -> store the element index i (used for sector row lists)
__global__ void csr_fill(const int* __restrict__ val, const int* __restrict__ key,
                         int* __restrict__ cursor, int* __restrict__ outl, int E)
{
  int i = blockIdx.x*256 + threadIdx.x;
  if (i >= E) return;
  int p = atomicAdd(&cursor[key[i]], 1);
  outl[p] = val ? val[i] : i;
}

// one wave per destination node: leaky-relu logits, max, denom, weighted gather
__global__ __launch_bounds__(256)
void gat_gather(const int* __restrict__ rowptr, const int* __restrict__ csrc,
                const float* __restrict__ es, const float* __restrict__ ed,
                const float* __restrict__ Hv, const float* __restrict__ bias,
                float* __restrict__ out, int n)
{
  int d = blockIdx.x*4 + (threadIdx.x >> 6);
  int l = threadIdx.x & 63;
  if (d >= n) return;
  const int p0 = rowptr[d], p1 = rowptr[d+1];
  const float edd = ed[d];
  float eself = es[d] + edd;
  eself = eself > 0.f ? eself : 0.2f*eself;
  float m = eself;
  for (int j = p0 + l; j < p1; j += 64){
    int s = csrc[j];
    float e = es[s] + edd;
    e = e > 0.f ? e : 0.2f*e;
    m = fmaxf(m, e);
  }
  #pragma unroll
  for (int off = 1; off < 64; off <<= 1) m = fmaxf(m, __shfl_xor(m, off, 64));
  float part = 0.f;
  for (int j = p0 + l; j < p1; j += 64){
    int s = csrc[j];
    float e = es[s] + edd;
    e = e > 0.f ? e : 0.2f*e;
    part += __expf(e - m);
  }
  #pragma unroll
  for (int off = 1; off < 64; off <<= 1) part += __shfl_xor(part, off, 64);
  const float wself = __expf(eself - m);
  const float inv = 1.f/(part + wself);
  float a = wself*inv;
  float acc0 = a * Hv[(long)d*HSZ + l];
  float acc1 = a * Hv[(long)d*HSZ + 64 + l];
  for (int j = p0; j < p1; ++j){
    int s = csrc[j];
    float e = es[s] + edd;
    e = e > 0.f ? e : 0.2f*e;
    float al = __expf(e - m)*inv;
    acc0 += al * Hv[(long)s*HSZ + l];
    acc1 += al * Hv[(long)s*HSZ + 64 + l];
  }
  out[(long)d*HSZ + l]      = acc0 + bias[l];
  out[(long)d*HSZ + 64 + l] = acc1 + bias[64 + l];
}

// per-sector max pool using sector row-list (CSR over sid)
__global__ __launch_bounds__(256)
void sector_pool(const float* __restrict__ intra, const int* __restrict__ srowptr,
                 const int* __restrict__ slist, float* __restrict__ spool)
{
  const int sec = blockIdx.x;
  const int t = threadIdx.x;
  const int d = t & 127, half = t >> 7;
  const int p0 = srowptr[sec], p1 = srowptr[sec+1];
  float m = -3.402823466e+38f;
  for (int j = p0 + half; j < p1; j += 2){
    int r = slist[j];
    m = fmaxf(m, intra[(long)r*HSZ + d]);
  }
  __shared__ float red[256];
  red[t] = m;
  __syncthreads();
  if (half == 0) spool[sec*HSZ + d] = fmaxf(red[d], red[128 + d]);
}

// ---- inter-sector GAT (tiny, keep atomic path) ----
__global__ void gat_init(unsigned* __restrict__ maxb, float* __restrict__ den,
                         float* __restrict__ acc, int n)
{
  long i = (long)blockIdx.x*256 + threadIdx.x;
  if (i < n){ maxb[i] = NEG_MAX_ORD; den[i] = 0.f; }
  if (i < (long)n*HSZ) acc[i] = 0.f;
}

__global__ void edge_max(const int* __restrict__ src, const int* __restrict__ dst,
                         const float* __restrict__ es, const float* __restrict__ ed,
                         unsigned* __restrict__ maxb, int E, int n)
{
  int i = blockIdx.x*256 + threadIdx.x;
  if (i >= E + n) return;
  int s, d;
  if (i < E){ s = src[i]; d = dst[i]; } else { s = d = i - E; }
  float e = es[s] + ed[d];
  e = e > 0.f ? e : 0.2f*e;
  atomicMax(maxb + d, fordu(e));
}

__global__ void edge_sum(const int* __restrict__ src, const int* __restrict__ dst,
                         const float* __restrict__ es, const float* __restrict__ ed,
                         const unsigned* __restrict__ maxb, float* __restrict__ den,
                         float* __restrict__ wbuf, int E, int n)
{
  int i = blockIdx.x*256 + threadIdx.x;
  if (i >= E + n) return;
  int s, d;
  if (i < E){ s = src[i]; d = dst[i]; } else { s = d = i - E; }
  float e = es[s] + ed[d];
  e = e > 0.f ? e : 0.2f*e;
  float w = __expf(e - unfordu(maxb[d]));
  wbuf[i] = w;
  atomicAdd(den + d, w);
}

__global__ void edge_scatter(const int* __restrict__ src, const int* __restrict__ dst,
                             const float* __restrict__ wbuf, const float* __restrict__ den,
                             const float* __restrict__ Hv, float* __restrict__ acc,
                             int E, int n)
{
  long t = (long)blockIdx.x*256 + threadIdx.x;
  long i = t >> 5;
  int  j = (int)(t & 31);
  if (i >= E + n) return;
  int s, d;
  if (i < E){ s = src[i]; d = dst[i]; } else { s = d = (int)(i - E); }
  float alpha = wbuf[i] / den[d];
  float4 hv = ((const float4*)(Hv + (long)s*HSZ))[j];
  float* o = acc + (long)d*HSZ + j*4;
  atomicAdd(o+0, alpha*hv.x);
  atomicAdd(o+1, alpha*hv.y);
  atomicAdd(o+2, alpha*hv.z);
  atomicAdd(o+3, alpha*hv.w);
}

__global__ void inter_bias_k(const float* __restrict__ acc2, const float* __restrict__ bias,
                             float* __restrict__ isec)
{
  int i = blockIdx.x*256 + threadIdx.x;   // exactly 64*128
  isec[i] = acc2[i] + bias[i & 127];
}

__global__ __launch_bounds__(256)
void fusion_k(const float* __restrict__ seq, const float* __restrict__ intra,
              const float* __restrict__ isec, const int* __restrict__ sid,
              const float* __restrict__ fw, const float* __restrict__ fb,
              float* __restrict__ out, int n)
{
  int i = blockIdx.x*4 + (threadIdx.x >> 6);
  int l = threadIdx.x & 63;
  if (i >= n) return;
  int sc = sid[i];
  long b = (long)i*HSZ;
  long sb = (long)sc*HSZ;
  float acc = fw[l]     * seq[b + l]      + fw[64 + l]  * seq[b + 64 + l]
            + fw[128+l] * intra[b + l]    + fw[192 + l] * intra[b + 64 + l]
            + fw[256+l] * isec[sb + l]    + fw[320 + l] * isec[sb + 64 + l];
  #pragma unroll
  for (int m = 1; m < 64; m <<= 1) acc += __shfl_xor(acc, m, 64);
  if (l == 0) out[i] = acc + fb[0];
}

extern "C" void kernel_launch(void* const* d_in, const int* in_sizes, int n_in,
                              void* d_out, int out_size, void* d_ws, size_t ws_size,
                              hipStream_t stream)
{
  const float* x    = (const float*)d_in[0];
  const int*   iei  = (const int*)d_in[1];    // [2, 640000]
  const int*   eei  = (const int*)d_in[2];    // [2, 4096]
  const int*   sid  = (const int*)d_in[3];
  const float* wih0 = (const float*)d_in[4];
  const float* whh0 = (const float*)d_in[5];
  const float* bih0 = (const float*)d_in[6];
  const float* bhh0 = (const float*)d_in[7];
  const float* wih1 = (const float*)d_in[8];
  const float* whh1 = (const float*)d_in[9];
  const float* bih1 = (const float*)d_in[10];
  const float* bhh1 = (const float*)d_in[11];
  const float* iW   = (const float*)d_in[12];
  const float* ias  = (const float*)d_in[13];
  const float* iad  = (const float*)d_in[14];
  const float* ib   = (const float*)d_in[15];
  const float* eW   = (const float*)d_in[16];
  const float* eas  = (const float*)d_in[17];
  const float* ead  = (const float*)d_in[18];
  const float* eb   = (const float*)d_in[19];
  const float* fW   = (const float*)d_in[20];
  const float* fb   = (const float*)d_in[21];

  float* ws = (float*)d_ws;
  long off = 0;
  float* seq    = ws + off; off += 2560000;
  float* hintra = ws + off; off += 2560000;
  float* intra  = ws + off; off += 2560000;
  float* es     = ws + off; off += 20000;
  float* ed     = ws + off; off += 20000;
  int*   cnt    = (int*)(ws + off); off += 20000;
  int*   rowptr = (int*)(ws + off); off += 20004;
  int*   cursor = (int*)(ws + off); off += 20000;
  int*   csrc   = (int*)(ws + off); off += 640000;
  int*   scnt    = (int*)(ws + off); off += 64;
  int*   srowptr = (int*)(ws + off); off += 68;
  int*   scursor = (int*)(ws + off); off += 64;
  int*   slist   = (int*)(ws + off); off += 20000;
  float* w0p = ws + off; off += 24576;   // bf16x3 pack: 2kt*24nt*2*1024B
  float* u0p = ws + off; off += 49152;   // 4kt
  float* w1p = ws + off; off += 49152;
  float* u1p = ws + off; off += 49152;
  float* spool  = ws + off; off += 8192;
  float* hinter = ws + off; off += 8192;
  float* acc2   = ws + off; off += 8192;
  float* es2    = ws + off; off += 64;
  float* ed2    = ws + off; off += 64;
  unsigned* mx2 = (unsigned*)(ws + off); off += 64;
  float* den2   = ws + off; off += 64;
  float* wbf2   = ws + off; off += 4160;
  float* isec   = ws + off; off += 8192;
  // total ~8.6M floats = ~34.5 MB

  // 0) pack GRU weights into bf16 hi/lo MFMA fragment layout
  wpack_mfma<<<12, 256, 0, stream>>>(wih0, (unsigned short*)w0p, 64);
  wpack_mfma<<<24, 256, 0, stream>>>(whh0, (unsigned short*)u0p, 128);
  wpack_mfma<<<24, 256, 0, stream>>>(wih1, (unsigned short*)w1p, 128);
  wpack_mfma<<<24, 256, 0, stream>>>(whh1, (unsigned short*)u1p, 128);

  // 1) MFMA bf16x3 fused 2-layer GRU -> seq_emb (250 blocks x 512 thr, M=80)
  gru_mfma<<<250, 512, 0, stream>>>(x,
                                    (const unsigned short*)w0p, (const unsigned short*)u0p,
                                    (const unsigned short*)w1p, (const unsigned short*)u1p,
                                    bih0, bhh0, bih1, bhh1, seq);

  // 2) intra GAT: transform + CSR build + atomic-free gather
  gat_transform<<<313, 256, 0, stream>>>(seq, iW, ias, iad, hintra, es, ed, NCOMP);
  zero_i   <<<(NCOMP+255)/256, 256, 0, stream>>>(cnt, NCOMP);
  zero_i   <<<1, 256, 0, stream>>>(scnt, NSEC);
  csr_count<<<(EINTRA+255)/256, 256, 0, stream>>>(iei + EINTRA, cnt, EINTRA);
  csr_count<<<(NCOMP+255)/256, 256, 0, stream>>>(sid, scnt, NCOMP);
  csr_scan <<<1, 1024, 0, stream>>>(cnt, rowptr, cursor, NCOMP);
  csr_scan <<<1, 1024, 0, stream>>>(scnt, srowptr, scursor, NSEC);
  csr_fill <<<(EINTRA+255)/256, 256, 0, stream>>>(iei, iei + EINTRA, cursor, csrc, EINTRA);
  csr_fill <<<(NCOMP+255)/256, 256, 0, stream>>>(nullptr, sid, scursor, slist, NCOMP);
  gat_gather<<<NCOMP/4, 256, 0, stream>>>(rowptr, csrc, es, ed, hintra, ib, intra, NCOMP);

  // 3) per-sector max pool via sector row lists
  sector_pool<<<NSEC, 256, 0, stream>>>(intra, srowptr, slist, spool);

  // 4) inter GAT (tiny: 64 nodes, 4096 edges — atomic path)
  gat_init<<<32, 256, 0, stream>>>(mx2, den2, acc2, NSEC);
  gat_transform<<<1, 256, 0, stream>>>(spool, eW, eas, ead, hinter, es2, ed2, NSEC);
  {
    int tot = EINTER + NSEC;
    edge_max    <<<(tot+255)/256, 256, 0, stream>>>(eei, eei+EINTER, es2, ed2, mx2, EINTER, NSEC);
    edge_sum    <<<(tot+255)/256, 256, 0, stream>>>(eei, eei+EINTER, es2, ed2, mx2, den2, wbf2, EINTER, NSEC);
    edge_scatter<<<(tot*32)/256, 256, 0, stream>>>(eei, eei+EINTER, wbf2, den2, hinter, acc2, EINTER, NSEC);
  }
  inter_bias_k<<<32, 256, 0, stream>>>(acc2, eb, isec);

  // 5) fusion -> output [20000]
  fusion_k<<<NCOMP/4, 256, 0, stream>>>(seq, intra, isec, sid, fW, fb, (float*)d_out, NCOMP);
}